// Round 4
// baseline (2925.142 us; speedup 1.0000x reference)
//
#include <hip/hip_runtime.h>

// RGCN encoder: N=20000 nodes, E=640000 edges, F=64, H=128, L=2 layers,
// D=3 edge-attr dims, R=8 relations, block-diag B=4 blocks of c=32.
//
// R4: R2 structure (128-thread block per dst node, lane-owned channels,
// broadcast elist loads) but LDS accumulation via result-unused atomicAdd
// -> fire-and-forget ds_add_f32 (no read-modify-write latency chain), and a
// 4-deep independent gather pipeline.

constexpr int H  = 128;
constexpr int F  = 64;
constexpr int D  = 3;
constexpr int R  = 8;
constexpr int B  = 4;
constexpr int C  = 32;
constexpr int ROWS = 8;     // gemm_h0
constexpr int ROWSB = 16;   // matB
constexpr int SCAN_CHUNK = 512;

// ---------------- CSR build (per-dst) ----------------

__global__ void count_edges(const int* __restrict__ ei, const int* __restrict__ attr,
                            int* __restrict__ cnt8, int E) {
  int e = blockIdx.x * 256 + threadIdx.x;
  if (e >= E) return;
  int dst = ei[E + e];
  #pragma unroll
  for (int j = 0; j < D; ++j) {
    int r = attr[e * D + j];
    atomicAdd(&cnt8[dst * (D * R) + j * R + r], 1);
  }
}

__global__ void indeg_from_cnt8(const int* __restrict__ cnt8, int* __restrict__ indeg, int N) {
  int n = blockIdx.x * 256 + threadIdx.x;
  if (n >= N) return;
  int s = 0;
  #pragma unroll
  for (int r = 0; r < R; ++r) s += cnt8[n * (D * R) + r];  // j=0 row counts each edge once
  indeg[n] = s;
}

__global__ void scan_a(const int* __restrict__ cnt, int* __restrict__ cexcl,
                       int* __restrict__ bsum, int nseg) {
  __shared__ int tmp[2][SCAN_CHUNK];
  int t = threadIdx.x;
  int gid = blockIdx.x * SCAN_CHUNK + t;
  int v = (gid < nseg) ? cnt[gid] : 0;
  int pa = 0;
  tmp[0][t] = v;
  __syncthreads();
  for (int off = 1; off < SCAN_CHUNK; off <<= 1) {
    tmp[1 - pa][t] = tmp[pa][t] + ((t >= off) ? tmp[pa][t - off] : 0);
    pa = 1 - pa;
    __syncthreads();
  }
  int incl = tmp[pa][t];
  if (gid < nseg) cexcl[gid] = incl - v;
  if (t == SCAN_CHUNK - 1) bsum[blockIdx.x] = incl;
}

__global__ void scan_b(int* __restrict__ bsum, int nblk) {
  __shared__ int tmp[2][1024];
  int t = threadIdx.x;
  int v = (t < nblk) ? bsum[t] : 0;
  int pa = 0;
  tmp[0][t] = v;
  __syncthreads();
  for (int off = 1; off < 1024; off <<= 1) {
    tmp[1 - pa][t] = tmp[pa][t] + ((t >= off) ? tmp[pa][t - off] : 0);
    pa = 1 - pa;
    __syncthreads();
  }
  if (t < nblk) bsum[t] = tmp[pa][t] - v;  // exclusive
}

__global__ void scan_c(const int* __restrict__ cexcl, const int* __restrict__ bsum,
                       int* __restrict__ offs, int nseg, int total) {
  int gid = blockIdx.x * 256 + threadIdx.x;
  if (gid < nseg) offs[gid] = cexcl[gid] + bsum[gid / SCAN_CHUNK];
  if (gid == 0) offs[nseg] = total;
}

__global__ void copy_int(const int* __restrict__ a, int* __restrict__ b, int n) {
  int i = blockIdx.x * 256 + threadIdx.x;
  if (i < n) b[i] = a[i];
}

__global__ void fill_edges(const int* __restrict__ ei, const int* __restrict__ attr,
                           int* __restrict__ cursor, unsigned* __restrict__ elist, int E) {
  int e = blockIdx.x * 256 + threadIdx.x;
  if (e >= E) return;
  int src = ei[e];
  int dst = ei[E + e];
  unsigned r0 = attr[e * D + 0], r1 = attr[e * D + 1], r2 = attr[e * D + 2];
  unsigned u = (unsigned)src | (r0 << 16) | (r1 << 20) | (r2 << 24);
  int p = atomicAdd(&cursor[dst], 1);
  elist[p] = u;
}

// ---------------- h0 = x @ emb ----------------

__global__ __launch_bounds__(128) void gemm_h0(const float* __restrict__ x,
                                               const float* __restrict__ emb,
                                               float* __restrict__ h0, int N) {
  __shared__ float xs[ROWS][F];
  int r0 = blockIdx.x * ROWS;
  for (int i = threadIdx.x; i < ROWS * F; i += 128)
    xs[i >> 6][i & 63] = x[(size_t)r0 * F + i];
  __syncthreads();
  int d = threadIdx.x;
  float acc[ROWS] = {};
  for (int k = 0; k < F; ++k) {
    float ev = emb[k * H + d];
    #pragma unroll
    for (int r = 0; r < ROWS; ++r) acc[r] = fmaf(xs[r][k], ev, acc[r]);
  }
  #pragma unroll
  for (int r = 0; r < ROWS; ++r) h0[(size_t)(r0 + r) * H + d] = acc[r];
}

// ---------------- aggregation + block-diag transform ----------------
// Block = 128 threads (2 waves) per dst node; thread d owns channel d.
// LDS accumulate via fire-and-forget ds_add_f32 (atomicAdd, result unused):
// no read-modify-write chain in the edge loop. 4 gathers in flight.

__global__ __launch_bounds__(128) void agg_kernel(
    const float* __restrict__ hsrc, const int* __restrict__ offs,
    const unsigned* __restrict__ elist, const int* __restrict__ cnt8,
    const float* __restrict__ Wall, float* __restrict__ m, int N) {
  const int n = blockIdx.x;
  const int d = threadIdx.x;
  __shared__ float s[D * R][H];   // 12 KB
  __shared__ float sinv[D * R];

  #pragma unroll
  for (int jr = 0; jr < D * R; ++jr) s[jr][d] = 0.f;
  if (d < D * R) {
    int c = cnt8[n * (D * R) + d];
    sinv[d] = (c > 0) ? 1.f / (float)c : 0.f;
  }
  // no barrier needed: each (jr,d) cell is zeroed and accumulated by thread d only

  const int beg = offs[n], end = offs[n + 1];
  int e0 = beg;
  for (; e0 + 4 <= end; e0 += 4) {
    const unsigned ua = elist[e0];
    const unsigned ub = elist[e0 + 1];
    const unsigned uc = elist[e0 + 2];
    const unsigned ud = elist[e0 + 3];
    const float va = hsrc[(size_t)(ua & 0xFFFFu) * H + d];
    const float vb = hsrc[(size_t)(ub & 0xFFFFu) * H + d];
    const float vc = hsrc[(size_t)(uc & 0xFFFFu) * H + d];
    const float vd = hsrc[(size_t)(ud & 0xFFFFu) * H + d];
    atomicAdd(&s[(ua >> 16) & 7][d], va);
    atomicAdd(&s[8 + ((ua >> 20) & 7)][d], va);
    atomicAdd(&s[16 + ((ua >> 24) & 7)][d], va);
    atomicAdd(&s[(ub >> 16) & 7][d], vb);
    atomicAdd(&s[8 + ((ub >> 20) & 7)][d], vb);
    atomicAdd(&s[16 + ((ub >> 24) & 7)][d], vb);
    atomicAdd(&s[(uc >> 16) & 7][d], vc);
    atomicAdd(&s[8 + ((uc >> 20) & 7)][d], vc);
    atomicAdd(&s[16 + ((uc >> 24) & 7)][d], vc);
    atomicAdd(&s[(ud >> 16) & 7][d], vd);
    atomicAdd(&s[8 + ((ud >> 20) & 7)][d], vd);
    atomicAdd(&s[16 + ((ud >> 24) & 7)][d], vd);
  }
  for (; e0 < end; ++e0) {
    const unsigned u = elist[e0];
    const float v = hsrc[(size_t)(u & 0xFFFFu) * H + d];
    atomicAdd(&s[(u >> 16) & 7][d], v);
    atomicAdd(&s[8 + ((u >> 20) & 7)][d], v);
    atomicAdd(&s[16 + ((u >> 24) & 7)][d], v);
  }
  __syncthreads();

  const int b = d >> 5, dd = d & 31;
  #pragma unroll
  for (int j = 0; j < D; ++j) {
    float acc = 0.f;
    for (int r = 0; r < R; ++r) {
      const int jr = j * R + r;
      const float* __restrict__ Wr = Wall + (((size_t)jr * B + b) * C) * C + dd;
      float t = 0.f;
      #pragma unroll
      for (int c = 0; c < C; ++c) t = fmaf(s[jr][b * C + c], Wr[(size_t)c * C], t);
      acc = fmaf(t, sinv[jr], acc);
    }
    m[((size_t)j * N + n) * H + d] = acc;
  }
}

// ---------------- dense root matmul + msg add + relu ----------------

__global__ __launch_bounds__(128) void matB(
    const float* __restrict__ h, const float* __restrict__ m,
    const float* __restrict__ rootall, const float* __restrict__ biasall,
    float* __restrict__ out, int N_all, int N) {
  const int j = blockIdx.y;
  const int row0 = blockIdx.x * ROWSB;
  const int d = threadIdx.x;
  const float* root = rootall + (size_t)j * H * H;
  __shared__ float hs[ROWSB][H];

  #pragma unroll
  for (int r = 0; r < ROWSB; ++r)
    hs[r][d] = h[(size_t)(row0 + r) * H + d];
  __syncthreads();

  const float bias = biasall[j * H + d];
  float acc[ROWSB];
  #pragma unroll
  for (int r = 0; r < ROWSB; ++r) acc[r] = bias;

  for (int k = 0; k < H; ++k) {
    float rk = root[(size_t)k * H + d];
    #pragma unroll
    for (int r = 0; r < ROWSB; ++r) acc[r] = fmaf(hs[r][k], rk, acc[r]);
  }

  if (row0 + ROWSB <= N) {
    #pragma unroll
    for (int r = 0; r < ROWSB; ++r)
      acc[r] += m[((size_t)j * N + row0 + r) * H + d];
  }

  #pragma unroll
  for (int r = 0; r < ROWSB; ++r)
    out[((size_t)j * N_all + row0 + r) * H + d] = fmaxf(acc[r], 0.f);
}

// ---------------- launch ----------------

extern "C" void kernel_launch(void* const* d_in, const int* in_sizes, int n_in,
                              void* d_out, int out_size, void* d_ws, size_t ws_size,
                              hipStream_t stream) {
  const float* x    = (const float*)d_in[0];
  const int*   ei   = (const int*)d_in[1];
  const int*   attr = (const int*)d_in[2];
  const float* emb  = (const float*)d_in[3];
  const float* cw   = (const float*)d_in[4];
  const float* cr   = (const float*)d_in[5];
  const float* cb   = (const float*)d_in[6];
  float* out = (float*)d_out;

  const int N = in_sizes[0] / F;   // 20000
  const int E = in_sizes[1] / 2;   // 640000

  char* ws = (char*)d_ws;
  size_t woff = 0;
  auto alloc = [&](size_t bytes) -> void* {
    void* p = ws + woff;
    woff = (woff + bytes + 255) & ~(size_t)255;
    return p;
  };
  float*    h0     = (float*)alloc((size_t)N * H * 4);
  float*    h1     = (float*)alloc((size_t)D * N * H * 4);
  float*    m      = (float*)alloc((size_t)D * N * H * 4);
  int*      indeg  = (int*)alloc((size_t)N * 4);
  int*      cnt8   = (int*)alloc((size_t)N * D * R * 4);
  int*      cexcl  = (int*)alloc((size_t)N * 4);
  int*      bsum   = (int*)alloc(4096);
  int*      offs   = (int*)alloc((size_t)(N + 1) * 4);
  int*      cursor = (int*)alloc((size_t)N * 4);
  unsigned* elist  = (unsigned*)alloc((size_t)E * 4);

  hipMemsetAsync(cnt8, 0, (size_t)N * D * R * 4, stream);
  count_edges<<<(E + 255) / 256, 256, 0, stream>>>(ei, attr, cnt8, E);
  indeg_from_cnt8<<<(N + 255) / 256, 256, 0, stream>>>(cnt8, indeg, N);

  int nch = (N + SCAN_CHUNK - 1) / SCAN_CHUNK;  // 40
  scan_a<<<nch, SCAN_CHUNK, 0, stream>>>(indeg, cexcl, bsum, N);
  scan_b<<<1, 1024, 0, stream>>>(bsum, nch);
  scan_c<<<(N + 255) / 256, 256, 0, stream>>>(cexcl, bsum, offs, N, E);
  copy_int<<<(N + 255) / 256, 256, 0, stream>>>(offs, cursor, N);
  fill_edges<<<(E + 255) / 256, 256, 0, stream>>>(ei, attr, cursor, elist, E);

  gemm_h0<<<N / ROWS, 128, 0, stream>>>(x, emb, h0, N);

  // layer 0
  agg_kernel<<<N, 128, 0, stream>>>(h0, offs, elist, cnt8, cw, m, N);
  {
    dim3 grid(N / ROWSB, D);
    matB<<<grid, 128, 0, stream>>>(h0, m, cr, cb, h1, N, N);
  }
  // layer 1 (gathers only rows < N of h1)
  agg_kernel<<<N, 128, 0, stream>>>(h1, offs, elist, cnt8,
                                    cw + (size_t)D * R * B * C * C, m, N);
  {
    dim3 grid((D * N) / ROWSB, D);
    matB<<<grid, 128, 0, stream>>>(h1, m,
                                   cr + (size_t)D * H * H,
                                   cb + (size_t)D * H,
                                   out, D * N, N);
  }
}

// Round 5
// 845.008 us; speedup vs baseline: 3.4617x; 3.4617x over previous
//
#include <hip/hip_runtime.h>

// RGCN encoder: N=20000 nodes, E=640000 edges, F=64, H=128, L=2 layers,
// D=3 edge-attr dims, R=8 relations, block-diag B=4 blocks of c=32.
//
// R5: agg edge loop is pure-VALU register accumulation. Each thread owns
// channel d and keeps acc[3][8] in VGPRs (compile-time indices only);
// relation selection via predicated adds (cmp+cndmask+add), NO LDS ops in
// the edge loop (R2 RMW chain / R3 shfl / R4 ds_add all serialized there).
// LDS used once afterwards to transpose for the block-diag transform.

constexpr int H  = 128;
constexpr int F  = 64;
constexpr int D  = 3;
constexpr int R  = 8;
constexpr int B  = 4;
constexpr int C  = 32;
constexpr int ROWS = 8;     // gemm_h0
constexpr int ROWSB = 16;   // matB
constexpr int SCAN_CHUNK = 512;

// ---------------- CSR build (per-dst) ----------------

__global__ void count_edges(const int* __restrict__ ei, const int* __restrict__ attr,
                            int* __restrict__ cnt8, int E) {
  int e = blockIdx.x * 256 + threadIdx.x;
  if (e >= E) return;
  int dst = ei[E + e];
  #pragma unroll
  for (int j = 0; j < D; ++j) {
    int r = attr[e * D + j];
    atomicAdd(&cnt8[dst * (D * R) + j * R + r], 1);
  }
}

__global__ void indeg_from_cnt8(const int* __restrict__ cnt8, int* __restrict__ indeg, int N) {
  int n = blockIdx.x * 256 + threadIdx.x;
  if (n >= N) return;
  int s = 0;
  #pragma unroll
  for (int r = 0; r < R; ++r) s += cnt8[n * (D * R) + r];  // j=0 row counts each edge once
  indeg[n] = s;
}

__global__ void scan_a(const int* __restrict__ cnt, int* __restrict__ cexcl,
                       int* __restrict__ bsum, int nseg) {
  __shared__ int tmp[2][SCAN_CHUNK];
  int t = threadIdx.x;
  int gid = blockIdx.x * SCAN_CHUNK + t;
  int v = (gid < nseg) ? cnt[gid] : 0;
  int pa = 0;
  tmp[0][t] = v;
  __syncthreads();
  for (int off = 1; off < SCAN_CHUNK; off <<= 1) {
    tmp[1 - pa][t] = tmp[pa][t] + ((t >= off) ? tmp[pa][t - off] : 0);
    pa = 1 - pa;
    __syncthreads();
  }
  int incl = tmp[pa][t];
  if (gid < nseg) cexcl[gid] = incl - v;
  if (t == SCAN_CHUNK - 1) bsum[blockIdx.x] = incl;
}

__global__ void scan_b(int* __restrict__ bsum, int nblk) {
  __shared__ int tmp[2][1024];
  int t = threadIdx.x;
  int v = (t < nblk) ? bsum[t] : 0;
  int pa = 0;
  tmp[0][t] = v;
  __syncthreads();
  for (int off = 1; off < 1024; off <<= 1) {
    tmp[1 - pa][t] = tmp[pa][t] + ((t >= off) ? tmp[pa][t - off] : 0);
    pa = 1 - pa;
    __syncthreads();
  }
  if (t < nblk) bsum[t] = tmp[pa][t] - v;  // exclusive
}

__global__ void scan_c(const int* __restrict__ cexcl, const int* __restrict__ bsum,
                       int* __restrict__ offs, int nseg, int total) {
  int gid = blockIdx.x * 256 + threadIdx.x;
  if (gid < nseg) offs[gid] = cexcl[gid] + bsum[gid / SCAN_CHUNK];
  if (gid == 0) offs[nseg] = total;
}

__global__ void copy_int(const int* __restrict__ a, int* __restrict__ b, int n) {
  int i = blockIdx.x * 256 + threadIdx.x;
  if (i < n) b[i] = a[i];
}

__global__ void fill_edges(const int* __restrict__ ei, const int* __restrict__ attr,
                           int* __restrict__ cursor, unsigned* __restrict__ elist, int E) {
  int e = blockIdx.x * 256 + threadIdx.x;
  if (e >= E) return;
  int src = ei[e];
  int dst = ei[E + e];
  unsigned r0 = attr[e * D + 0], r1 = attr[e * D + 1], r2 = attr[e * D + 2];
  unsigned u = (unsigned)src | (r0 << 16) | (r1 << 20) | (r2 << 24);
  int p = atomicAdd(&cursor[dst], 1);
  elist[p] = u;
}

// ---------------- h0 = x @ emb ----------------

__global__ __launch_bounds__(128) void gemm_h0(const float* __restrict__ x,
                                               const float* __restrict__ emb,
                                               float* __restrict__ h0, int N) {
  __shared__ float xs[ROWS][F];
  int r0 = blockIdx.x * ROWS;
  for (int i = threadIdx.x; i < ROWS * F; i += 128)
    xs[i >> 6][i & 63] = x[(size_t)r0 * F + i];
  __syncthreads();
  int d = threadIdx.x;
  float acc[ROWS] = {};
  for (int k = 0; k < F; ++k) {
    float ev = emb[k * H + d];
    #pragma unroll
    for (int r = 0; r < ROWS; ++r) acc[r] = fmaf(xs[r][k], ev, acc[r]);
  }
  #pragma unroll
  for (int r = 0; r < ROWS; ++r) h0[(size_t)(r0 + r) * H + d] = acc[r];
}

// ---------------- aggregation + block-diag transform ----------------
// Block = 128 threads per dst node; thread d owns channel d.
// acc[3][8] lives in VGPRs; relation select via predicated adds (pure VALU).

__global__ __launch_bounds__(128) void agg_kernel(
    const float* __restrict__ hsrc, const int* __restrict__ offs,
    const unsigned* __restrict__ elist, const int* __restrict__ cnt8,
    const float* __restrict__ Wall, float* __restrict__ m, int N) {
  const int n = blockIdx.x;
  const int d = threadIdx.x;
  __shared__ float s[D * R][H];   // 12 KB (transpose staging only)
  __shared__ float sinv[D * R];

  float acc[D][R];
  #pragma unroll
  for (int j = 0; j < D; ++j)
    #pragma unroll
    for (int r = 0; r < R; ++r) acc[j][r] = 0.f;

  if (d < D * R) {
    int c = cnt8[n * (D * R) + d];
    sinv[d] = (c > 0) ? 1.f / (float)c : 0.f;
  }

  const int beg = offs[n], end = offs[n + 1];

  auto ACC = [&](unsigned u, float v) {
    #pragma unroll
    for (int j = 0; j < D; ++j) {
      const unsigned rel = (u >> (16 + 4 * j)) & 7u;
      #pragma unroll
      for (int r = 0; r < R; ++r)
        acc[j][r] += (rel == (unsigned)r) ? v : 0.f;
    }
  };

  int e = beg;
  for (; e + 4 <= end; e += 4) {
    const unsigned u0 = elist[e], u1 = elist[e + 1];
    const unsigned u2 = elist[e + 2], u3 = elist[e + 3];
    const float v0 = hsrc[(size_t)(u0 & 0xFFFFu) * H + d];
    const float v1 = hsrc[(size_t)(u1 & 0xFFFFu) * H + d];
    const float v2 = hsrc[(size_t)(u2 & 0xFFFFu) * H + d];
    const float v3 = hsrc[(size_t)(u3 & 0xFFFFu) * H + d];
    ACC(u0, v0); ACC(u1, v1); ACC(u2, v2); ACC(u3, v3);
  }
  for (; e < end; ++e) {
    const unsigned u = elist[e];
    const float v = hsrc[(size_t)(u & 0xFFFFu) * H + d];
    ACC(u, v);
  }

  // transpose to LDS for the cross-channel transform
  #pragma unroll
  for (int j = 0; j < D; ++j)
    #pragma unroll
    for (int r = 0; r < R; ++r) s[j * R + r][d] = acc[j][r];
  __syncthreads();

  const int b = d >> 5, dd = d & 31;
  #pragma unroll
  for (int j = 0; j < D; ++j) {
    float a = 0.f;
    for (int r = 0; r < R; ++r) {
      const int jr = j * R + r;
      const float* __restrict__ Wr = Wall + (((size_t)jr * B + b) * C) * C + dd;
      const float4* __restrict__ srow4 = (const float4*)&s[jr][b * C];
      float t = 0.f;
      #pragma unroll
      for (int c4 = 0; c4 < C / 4; ++c4) {
        const float4 sv = srow4[c4];
        t = fmaf(sv.x, Wr[(size_t)(4 * c4 + 0) * C], t);
        t = fmaf(sv.y, Wr[(size_t)(4 * c4 + 1) * C], t);
        t = fmaf(sv.z, Wr[(size_t)(4 * c4 + 2) * C], t);
        t = fmaf(sv.w, Wr[(size_t)(4 * c4 + 3) * C], t);
      }
      a = fmaf(t, sinv[jr], a);
    }
    m[((size_t)j * N + n) * H + d] = a;
  }
}

// ---------------- dense root matmul + msg add + relu ----------------

__global__ __launch_bounds__(128) void matB(
    const float* __restrict__ h, const float* __restrict__ m,
    const float* __restrict__ rootall, const float* __restrict__ biasall,
    float* __restrict__ out, int N_all, int N) {
  const int j = blockIdx.y;
  const int row0 = blockIdx.x * ROWSB;
  const int d = threadIdx.x;
  const float* root = rootall + (size_t)j * H * H;
  __shared__ float hs[ROWSB][H];

  #pragma unroll
  for (int r = 0; r < ROWSB; ++r)
    hs[r][d] = h[(size_t)(row0 + r) * H + d];
  __syncthreads();

  const float bias = biasall[j * H + d];
  float acc[ROWSB];
  #pragma unroll
  for (int r = 0; r < ROWSB; ++r) acc[r] = bias;

  for (int k = 0; k < H; ++k) {
    float rk = root[(size_t)k * H + d];
    #pragma unroll
    for (int r = 0; r < ROWSB; ++r) acc[r] = fmaf(hs[r][k], rk, acc[r]);
  }

  if (row0 + ROWSB <= N) {
    #pragma unroll
    for (int r = 0; r < ROWSB; ++r)
      acc[r] += m[((size_t)j * N + row0 + r) * H + d];
  }

  #pragma unroll
  for (int r = 0; r < ROWSB; ++r)
    out[((size_t)j * N_all + row0 + r) * H + d] = fmaxf(acc[r], 0.f);
}

// ---------------- launch ----------------

extern "C" void kernel_launch(void* const* d_in, const int* in_sizes, int n_in,
                              void* d_out, int out_size, void* d_ws, size_t ws_size,
                              hipStream_t stream) {
  const float* x    = (const float*)d_in[0];
  const int*   ei   = (const int*)d_in[1];
  const int*   attr = (const int*)d_in[2];
  const float* emb  = (const float*)d_in[3];
  const float* cw   = (const float*)d_in[4];
  const float* cr   = (const float*)d_in[5];
  const float* cb   = (const float*)d_in[6];
  float* out = (float*)d_out;

  const int N = in_sizes[0] / F;   // 20000
  const int E = in_sizes[1] / 2;   // 640000

  char* ws = (char*)d_ws;
  size_t woff = 0;
  auto alloc = [&](size_t bytes) -> void* {
    void* p = ws + woff;
    woff = (woff + bytes + 255) & ~(size_t)255;
    return p;
  };
  float*    h0     = (float*)alloc((size_t)N * H * 4);
  float*    h1     = (float*)alloc((size_t)D * N * H * 4);
  float*    m      = (float*)alloc((size_t)D * N * H * 4);
  int*      indeg  = (int*)alloc((size_t)N * 4);
  int*      cnt8   = (int*)alloc((size_t)N * D * R * 4);
  int*      cexcl  = (int*)alloc((size_t)N * 4);
  int*      bsum   = (int*)alloc(4096);
  int*      offs   = (int*)alloc((size_t)(N + 1) * 4);
  int*      cursor = (int*)alloc((size_t)N * 4);
  unsigned* elist  = (unsigned*)alloc((size_t)E * 4);

  hipMemsetAsync(cnt8, 0, (size_t)N * D * R * 4, stream);
  count_edges<<<(E + 255) / 256, 256, 0, stream>>>(ei, attr, cnt8, E);
  indeg_from_cnt8<<<(N + 255) / 256, 256, 0, stream>>>(cnt8, indeg, N);

  int nch = (N + SCAN_CHUNK - 1) / SCAN_CHUNK;  // 40
  scan_a<<<nch, SCAN_CHUNK, 0, stream>>>(indeg, cexcl, bsum, N);
  scan_b<<<1, 1024, 0, stream>>>(bsum, nch);
  scan_c<<<(N + 255) / 256, 256, 0, stream>>>(cexcl, bsum, offs, N, E);
  copy_int<<<(N + 255) / 256, 256, 0, stream>>>(offs, cursor, N);
  fill_edges<<<(E + 255) / 256, 256, 0, stream>>>(ei, attr, cursor, elist, E);

  gemm_h0<<<N / ROWS, 128, 0, stream>>>(x, emb, h0, N);

  // layer 0
  agg_kernel<<<N, 128, 0, stream>>>(h0, offs, elist, cnt8, cw, m, N);
  {
    dim3 grid(N / ROWSB, D);
    matB<<<grid, 128, 0, stream>>>(h0, m, cr, cb, h1, N, N);
  }
  // layer 1 (gathers only rows < N of h1)
  agg_kernel<<<N, 128, 0, stream>>>(h1, offs, elist, cnt8,
                                    cw + (size_t)D * R * B * C * C, m, N);
  {
    dim3 grid((D * N) / ROWSB, D);
    matB<<<grid, 128, 0, stream>>>(h1, m,
                                   cr + (size_t)D * H * H,
                                   cb + (size_t)D * H,
                                   out, D * N, N);
  }
}